// Round 2
// baseline (144.919 us; speedup 1.0000x reference)
//
#include <hip/hip_runtime.h>
#include <math.h>

typedef _Float16 half8  __attribute__((ext_vector_type(8)));
typedef _Float16 half4v __attribute__((ext_vector_type(4)));
typedef float    f32x4  __attribute__((ext_vector_type(4)));
typedef float    f32x2  __attribute__((ext_vector_type(2)));
typedef float    f32x16 __attribute__((ext_vector_type(16)));

// swizzled-weight offsets in halfs inside d_ws (32x32x16 fragment layout)
#define W1OFF 0        // 8 MT-tiles * 64 lanes * 8 = 4096 halfs (K padded 2->16)
#define W2OFF 4096     // 16 kk * 8 MT * 64 * 8 = 65536
#define W3OFF 69632    // 65536
#define W4OFF 135168   // 16x16 frags: 8 kkb * 64 * 8 = 4096 (N padded 3->16)
#define SWTOT 139264
#define OUT_PIX (16*128*128)

// ---------------- prep: swizzle weights (fp32 -> f16 frag-contiguous) + dx/dy tail ----
// 32x32x16 A-frag: lane holds A[m = MT*32 + (lane&31)][k = kk*16 + (lane>>5)*8 + j]
__global__ void inr_prep(const float* __restrict__ W1, const float* __restrict__ W2,
                         const float* __restrict__ W3, const float* __restrict__ W4,
                         const int* __restrict__ sidx, const float* __restrict__ sv,
                         _Float16* __restrict__ wsw, float* __restrict__ outtail)
{
    int tid = blockIdx.x * 256 + threadIdx.x;
    if (tid < 16) {
        int si = sidx[tid];
        outtail[tid]      = sv[2*si + 1];   // dx = shift[:,1]
        outtail[16 + tid] = sv[2*si + 0];   // dy = shift[:,0]
    }
    if (tid >= SWTOT) return;
    int kind, rel;
    if      (tid < W2OFF) { kind = 0; rel = tid; }
    else if (tid < W3OFF) { kind = 1; rel = tid - W2OFF; }
    else if (tid < W4OFF) { kind = 2; rel = tid - W3OFF; }
    else                  { kind = 3; rel = tid - W4OFF; }
    int j    = rel & 7;
    int lane = (rel >> 3) & 63;
    int blk  = rel >> 9;
    float val;
    if (kind == 3) {                       // W4 (16x16 frag): A[m][k] = W4[k][m], m<3 else 0
        int q = lane >> 4, ln = lane & 15;
        int m = ln;
        int k = blk * 32 + q * 8 + j;
        val = (m < 3) ? W4[k*3 + m] : 0.0f;
    } else {
        int hi = lane >> 5, lo = lane & 31;
        if (kind == 0) {                   // W1: one kk (K padded 2->16), blk = MT
            int m = blk*32 + lo;
            int k = hi*8 + j;
            val = (k < 2) ? W1[k*256 + m] : 0.0f;
        } else {                           // W2/W3: blk = kk*8 + MT
            int MT = blk & 7, kk = blk >> 3;
            int m = MT*32 + lo;
            int k = kk*16 + hi*8 + j;
            val = (kind == 1) ? W2[k*256 + m] : W3[k*256 + m];
        }
    }
    wsw[tid] = (_Float16)val;
}

// ---------------- fused MLP ----------------
// LDS activation layout: granule-major.  Element (pixel, hid) lives at
//   hbuf[(hid>>3)*1024 + pixel*8 + (hid&7)]     (granule = 8 halfs = 16 B, 128 px)
//
// 32x32x16 MFMA: wave w owns MT {2w, 2w+1} (64 hids) x all 128 px (4 NT of 32).
// B-frag: lane reads act[k = kk*16 + (lane>>5)*8 + j][px = nt*32 + (lane&31)]
//   -> granule g = kk*2 + (lane>>5), one ds_read_b128 at hbuf[g*1024 + px*8].
// C/D:   col = lane&31 (px), row = (reg&3) + 8*(reg>>2) + 4*(lane>>5).
template<int NKK>
__device__ __forceinline__ void do_layer32(const half8* __restrict__ Asw,
                                           const float* __restrict__ bias,
                                           _Float16* hbuf, int w, int lane)
{
    int lo = lane & 31, hi = lane >> 5;
    f32x16 acc[2][4];
#pragma unroll
    for (int mt = 0; mt < 2; ++mt)
#pragma unroll
        for (int nt = 0; nt < 4; ++nt)
#pragma unroll
            for (int r = 0; r < 16; ++r)
                acc[mt][nt][r] = 0.f;

#pragma unroll
    for (int kk = 0; kk < NKK; ++kk) {
        half8 aw[2];                                   // weights: global dwordx4, L2-hot
#pragma unroll
        for (int mt = 0; mt < 2; ++mt)
            aw[mt] = Asw[(kk*8 + 2*w + mt)*64 + lane];
        half8 bf[4];                                   // activations: ds_read_b128
        int g = kk*2 + hi;
#pragma unroll
        for (int nt = 0; nt < 4; ++nt)
            bf[nt] = *(const half8*)&hbuf[g*1024 + (32*nt + lo)*8];
#pragma unroll
        for (int nt = 0; nt < 4; ++nt)
#pragma unroll
            for (int mt = 0; mt < 2; ++mt)
                acc[mt][nt] = __builtin_amdgcn_mfma_f32_32x32x16_f16(aw[mt], bf[nt], acc[mt][nt], 0, 0, 0);
    }
    __syncthreads();                                   // all reads of hbuf done
    // epilogue: bias + relu + f16 cast; 4 consecutive hids per reg-quad -> one b64 write
#pragma unroll
    for (int mt = 0; mt < 2; ++mt) {
        int MT = 2*w + mt;
#pragma unroll
        for (int gi = 0; gi < 4; ++gi) {
            int hid0 = MT*32 + gi*8 + 4*hi;
            f32x4 bv = *(const f32x4*)&bias[hid0];
#pragma unroll
            for (int nt = 0; nt < 4; ++nt) {
                int px = 32*nt + lo;
                half4v hv;
                hv[0] = (_Float16)fmaxf(acc[mt][nt][gi*4+0] + bv[0], 0.f);
                hv[1] = (_Float16)fmaxf(acc[mt][nt][gi*4+1] + bv[1], 0.f);
                hv[2] = (_Float16)fmaxf(acc[mt][nt][gi*4+2] + bv[2], 0.f);
                hv[3] = (_Float16)fmaxf(acc[mt][nt][gi*4+3] + bv[3], 0.f);
                *(half4v*)&hbuf[(MT*4 + gi)*1024 + px*8 + 4*hi] = hv;
            }
        }
    }
    __syncthreads();
}

__launch_bounds__(256, 2)
__global__ void inr_fused(const float* __restrict__ x, const int* __restrict__ sidx_p,
                          const float* __restrict__ sv, const float* __restrict__ ra,
                          const float* __restrict__ cs, const float* __restrict__ csh,
                          const float* __restrict__ b1, const float* __restrict__ b2,
                          const float* __restrict__ b3, const float* __restrict__ b4,
                          const _Float16* __restrict__ wsw, float* __restrict__ out)
{
    __shared__ __align__(16) _Float16 hbuf[32768];     // 128 px x 256 hid, 64 KB
    int t = threadIdx.x;
    int lane = t & 63, w = t >> 6, q = lane >> 4, ln = lane & 15;
    int pixbase = blockIdx.x * 128;
    int b = pixbase >> 14;                             // 16384 px per image
    int sidx = sidx_p[b];
    float dy = sv[2*sidx], dx = sv[2*sidx + 1];
    float ang = ra[sidx];
    float sn, cn;
    sincosf(ang, &sn, &cn);

    // stage coords: layer-1 K=16 -> granules 0,1 only; uv at hid 0,1
    if (t < 128) {
        int p = t;
        f32x2 xv = *(const f32x2*)&x[(pixbase + p)*2];
        float u = cn*xv[0] - sn*xv[1] + dx;
        float v = sn*xv[0] + cn*xv[1] + dy;
        half8 z;
#pragma unroll
        for (int i = 0; i < 8; ++i) z[i] = (_Float16)0.0f;
        z[0] = (_Float16)u; z[1] = (_Float16)v;
        *(half8*)&hbuf[0*1024 + p*8] = z;
    } else {
        int p = t - 128;
        half8 z;
#pragma unroll
        for (int i = 0; i < 8; ++i) z[i] = (_Float16)0.0f;
        *(half8*)&hbuf[1*1024 + p*8] = z;
    }
    __syncthreads();

    const half8* wsw8 = (const half8*)wsw;
    do_layer32<1>(wsw8,                b1, hbuf, w, lane);   // layer 1 (K=16 padded)
    do_layer32<16>(wsw8 + (W2OFF >> 3), b2, hbuf, w, lane);  // layer 2
    do_layer32<16>(wsw8 + (W3OFF >> 3), b3, hbuf, w, lane);  // layer 3

    // layer 4: 16x16 (M=16, 3 real), each wave -> 32 pixels
    const half8* w4p = wsw8 + (W4OFF >> 3);
    f32x4 a4[2];
    a4[0] = (f32x4){0.f,0.f,0.f,0.f};
    a4[1] = (f32x4){0.f,0.f,0.f,0.f};
#pragma unroll
    for (int kkb = 0; kkb < 8; ++kkb) {
        half8 aw = w4p[kkb*64 + lane];
#pragma unroll
        for (int i = 0; i < 2; ++i) {
            int pixel = 16*(2*w + i) + ln;
            half8 bf = *(const half8*)&hbuf[(kkb*4 + q)*1024 + pixel*8];
            a4[i] = __builtin_amdgcn_mfma_f32_16x16x32_f16(aw, bf, a4[i], 0, 0, 0);
        }
    }
    if (q == 0) {                                      // rows 0..2 = output channels
        bool doc = (sidx != 0);
        float s0 = cs[sidx*3+0], s1 = cs[sidx*3+1], s2 = cs[sidx*3+2];
        float t0 = csh[sidx*3+0], t1 = csh[sidx*3+1], t2 = csh[sidx*3+2];
        float bb0 = b4[0], bb1 = b4[1], bb2 = b4[2];
#pragma unroll
        for (int i = 0; i < 2; ++i) {
            int gp = pixbase + 16*(2*w + i) + ln;
            float v0 = a4[i][0] + bb0;
            float v1 = a4[i][1] + bb1;
            float v2 = a4[i][2] + bb2;
            if (doc) { v0 = v0*s0 + t0; v1 = v1*s1 + t1; v2 = v2*s2 + t2; }
            out[gp*3 + 0] = v0;
            out[gp*3 + 1] = v1;
            out[gp*3 + 2] = v2;
        }
    }
}

extern "C" void kernel_launch(void* const* d_in, const int* in_sizes, int n_in,
                              void* d_out, int out_size, void* d_ws, size_t ws_size,
                              hipStream_t stream)
{
    const float* x    = (const float*)d_in[0];
    const int*   sidx = (const int*)  d_in[1];
    const float* sv   = (const float*)d_in[2];
    const float* ra   = (const float*)d_in[3];
    const float* cs   = (const float*)d_in[4];
    const float* csh  = (const float*)d_in[5];
    const float* W1   = (const float*)d_in[6];
    const float* b1   = (const float*)d_in[7];
    const float* W2   = (const float*)d_in[8];
    const float* b2   = (const float*)d_in[9];
    const float* W3   = (const float*)d_in[10];
    const float* b3   = (const float*)d_in[11];
    const float* W4   = (const float*)d_in[12];
    const float* b4   = (const float*)d_in[13];
    float* out = (float*)d_out;
    _Float16* wsw = (_Float16*)d_ws;

    inr_prep<<<SWTOT/256, 256, 0, stream>>>(W1, W2, W3, W4, sidx, sv, wsw, out + OUT_PIX*3);
    inr_fused<<<OUT_PIX/128, 256, 0, stream>>>(x, sidx, sv, ra, cs, csh,
                                               b1, b2, b3, b4, wsw, out);
}